// Round 3
// baseline (10336.977 us; speedup 1.0000x reference)
//
#include <hip/hip_runtime.h>
#include <cstdint>
#include <cstddef>

typedef unsigned int u32;
typedef unsigned short u16;
typedef __attribute__((ext_vector_type(8))) short s16x8;
typedef __attribute__((ext_vector_type(4))) float f32x4;

#define MFMA(a,b,c) __builtin_amdgcn_mfma_f32_16x16x32_bf16((a),(b),(c),0,0,0)

__device__ __forceinline__ u32 f2bf(float f){ union{float f;u32 u;}v; v.f=f; return (v.u + 0x7FFFu + ((v.u>>16)&1u))>>16; }
__device__ __forceinline__ float sigm(float x){ return __builtin_amdgcn_rcpf(1.0f + __builtin_amdgcn_exp2f(-1.4426950408889634f*x)); }
__device__ __forceinline__ float tanh_(float x){ return 1.0f - 2.0f*__builtin_amdgcn_rcpf(1.0f + __builtin_amdgcn_exp2f(2.8853900817779268f*x)); }

// node_init (fp32) -> shadow (bf16), whole tree. total8 = elements/8.
__global__ void conv_nodes(const float* __restrict__ src, u16* __restrict__ dst, long total8) {
    long i = (long)blockIdx.x*256 + threadIdx.x;
    const long stride = (long)gridDim.x*256;
    for (; i < total8; i += stride) {
        const float* s = src + i*8;
        float4 f0 = *(const float4*)s;
        float4 f1 = *(const float4*)(s+4);
        uint4 pk;
        pk.x = f2bf(f0.x) | (f2bf(f0.y)<<16);
        pk.y = f2bf(f0.z) | (f2bf(f0.w)<<16);
        pk.z = f2bf(f1.x) | (f2bf(f1.y)<<16);
        pk.w = f2bf(f1.z) | (f2bf(f1.w)<<16);
        *(uint4*)(dst + i*8) = pk;
    }
}

// Gate-interleaved row permutation: permuted row p (wave wv owns [wv*256,wv*256+256))
// p = wv*256 + gate*64 + u*16 + lrow  <->  source row = gate*256 + (wv*64 + u*16 + lrow)
__device__ __forceinline__ int srcrow(int p){ return ((p>>6)&3)*256 + ((p>>8)<<6) + (p&63); }

__global__ void prep_weights(const float* Wih_l, const float* Whh_l, const float* bih_l, const float* bhh_l,
                             const float* Wih_r, const float* Whh_r, const float* bih_r, const float* bhh_r,
                             const float* Wenc, const float* benc,
                             u16* wil, u16* whl, u16* wir, u16* whr, u16* we,
                             float* bl, float* br, float* be) {
    const int b = blockIdx.x, t = threadIdx.x;
    if (b < 1024) {
        int s = srcrow(b)*256 + t;
        int d = b*256 + t;
        wil[d]=(u16)f2bf(Wih_l[s]); whl[d]=(u16)f2bf(Whh_l[s]);
        wir[d]=(u16)f2bf(Wih_r[s]); whr[d]=(u16)f2bf(Whh_r[s]);
    } else if (b < 1536) {
        int e = (b-1024)*256 + t;
        we[e] = (u16)f2bf(Wenc[e]);
    } else {
        for (int j=0;j<4;++j){ int p=j*256+t; int s=srcrow(p); bl[p]=bih_l[s]+bhh_l[s]; br[p]=bih_r[s]+bhh_r[s]; }
        be[t] = benc[t];
    }
}

// One tree level. WG = NH*16 nodes, 256 threads (4 waves). Wave wv computes all 4
// gates for features [wv*64, wv*64+64) via gate-interleaved weights; cell update in
// registers; h deferred-scattered to LDS. el: non-leaf -> dead child-slot in shadow;
// leaf -> h_lds (el) / x_lds (er) swap.
template<int NH>
__launch_bounds__(256, 2)
__global__ void level_kernel(u16* __restrict__ shadow,
    const u16* __restrict__ wil, const u16* __restrict__ whl,
    const u16* __restrict__ wir, const u16* __restrict__ whr,
    const u16* __restrict__ we, const float* __restrict__ bl,
    const float* __restrict__ br, const float* __restrict__ be,
    float* __restrict__ dout,
    int off, int coff, int n, int T, int is_leaf, int is_root)
{
    __shared__ u16 x_lds[NH*16][264];
    __shared__ u16 h_lds[NH*16][264];

    const int tid = threadIdx.x;
    const int wv = tid>>6, lane = tid&63, lrow = lane&15, quad = lane>>4;
    const int nb = blockIdx.x * (NH*16);

    float c_reg[4*NH*4];
    u32 h_pack[4*NH*2];

    for (int side=0; side<2; ++side) {
        const u16* Wih = side? wir : wil;
        const u16* Whh = side? whr : whl;
        const float* bias = side? br : bl;
        for (int t=0; t<T; ++t) {
            // ---- stage phase: flush prev h_pack -> h_lds; stage x tile ----
            const bool wr_h = (t>0) || (side==1 && is_leaf);
            if (wr_h) {
#pragma unroll
                for (int u=0; u<4; ++u)
#pragma unroll
                for (int hf=0; hf<NH; ++hf)
#pragma unroll
                for (int rp=0; rp<2; ++rp) {
                    u32 p = h_pack[(u*NH+hf)*2+rp];
                    int node = hf*16 + quad*4 + rp*2;
                    int col = wv*64 + u*16 + lrow;
                    h_lds[node][col]   = (u16)p;
                    h_lds[node+1][col] = (u16)(p>>16);
                }
            }
            if (!(is_leaf && side==1)) {   // leaf side1 reuses own already in x_lds
                const bool own = is_leaf || (side==0 ? (t==T-1) : (t==0));
                int row = tid>>2;
                if (row < NH*16) {
                    int gn = nb + row; if (gn>=n) gn = n-1;
                    int cidx = (side==0)? (3-t) : (3+t);
                    size_t grow = own ? (size_t)(off+gn) : ((size_t)coff + (size_t)gn*8 + cidx);
                    const u16* s = shadow + grow*256 + (tid&3)*64;
                    u16* d = &x_lds[row][(tid&3)*64];
#pragma unroll
                    for (int q=0;q<8;++q) ((uint4*)d)[q] = ((const uint4*)s)[q];
                }
            }
            __syncthreads();

            // ---- GEMM (x@Wih^T [+ h@Whh^T]) + in-register cell update ----
            const bool el_glob = (!is_leaf) && side==0 && t==T-1;
#pragma unroll
            for (int u=0; u<4; ++u) {
                f32x4 acc[4][NH];
#pragma unroll
                for (int g=0; g<4; ++g) {
                    float bv = bias[wv*256 + g*64 + u*16 + lrow];
#pragma unroll
                    for (int hf=0; hf<NH; ++hf) acc[g][hf] = (f32x4){bv,bv,bv,bv};
                }
#pragma unroll
                for (int kc=0; kc<8; ++kc) {
                    s16x8 a[NH];
#pragma unroll
                    for (int hf=0; hf<NH; ++hf)
                        a[hf] = *(const s16x8*)&x_lds[hf*16+lrow][kc*32 + quad*8];
#pragma unroll
                    for (int g=0; g<4; ++g) {
                        s16x8 bw = *(const s16x8*)(Wih + (size_t)(wv*256+g*64+u*16+lrow)*256 + kc*32 + quad*8);
#pragma unroll
                        for (int hf=0; hf<NH; ++hf) acc[g][hf] = MFMA(a[hf], bw, acc[g][hf]);
                    }
                }
                if (t>0) {
#pragma unroll
                    for (int kc=0; kc<8; ++kc) {
                        s16x8 a[NH];
#pragma unroll
                        for (int hf=0; hf<NH; ++hf)
                            a[hf] = *(const s16x8*)&h_lds[hf*16+lrow][kc*32 + quad*8];
#pragma unroll
                        for (int g=0; g<4; ++g) {
                            s16x8 bw = *(const s16x8*)(Whh + (size_t)(wv*256+g*64+u*16+lrow)*256 + kc*32 + quad*8);
#pragma unroll
                            for (int hf=0; hf<NH; ++hf) acc[g][hf] = MFMA(a[hf], bw, acc[g][hf]);
                        }
                    }
                }
#pragma unroll
                for (int hf=0; hf<NH; ++hf) {
#pragma unroll
                    for (int r=0; r<4; ++r) {
                        float iv = sigm(acc[0][hf][r]);
                        float fv = sigm(acc[1][hf][r]);
                        float gv = tanh_(acc[2][hf][r]);
                        float ov = sigm(acc[3][hf][r]);
                        int ci = (u*NH+hf)*4 + r;
                        float c = iv*gv; if (t>0) c += fv*c_reg[ci];
                        c_reg[ci] = c;
                        float h = ov*tanh_(c);
                        u32 hb = f2bf(h);
                        if (el_glob) {
                            int node = hf*16+quad*4+r;
                            int gn = nb+node; if (gn>=n) gn=n-1;
                            shadow[((size_t)coff + (size_t)gn*8)*256 + wv*64+u*16+lrow] = (u16)hb;
                        } else {
                            int pi = (u*NH+hf)*2 + (r>>1);
                            if ((r&1)==0) h_pack[pi] = hb; else h_pack[pi] |= hb<<16;
                        }
                    }
                }
            }
            __syncthreads();
        } // t
    } // side

    // ---- encoder: scatter er (h_pack) -> (leaf? x_lds : h_lds) ----
#pragma unroll
    for (int u=0; u<4; ++u)
#pragma unroll
    for (int hf=0; hf<NH; ++hf)
#pragma unroll
    for (int rp=0; rp<2; ++rp) {
        u32 p = h_pack[(u*NH+hf)*2+rp];
        int node = hf*16 + quad*4 + rp*2;
        int col = wv*64 + u*16 + lrow;
        u16* d0 = is_leaf ? &x_lds[node][col] : &h_lds[node][col];
        d0[0]   = (u16)p;
        d0[264] = (u16)(p>>16);
    }
    __syncthreads();

    f32x4 acc2[4][NH];
#pragma unroll
    for (int u2=0; u2<4; ++u2) {
        int ce = wv*64 + u2*16 + lrow;
        float bv = be[ce];
#pragma unroll
        for (int hf=0; hf<NH; ++hf) acc2[u2][hf] = (f32x4){bv,bv,bv,bv};
#pragma unroll
        for (int kc=0; kc<8; ++kc) {
            s16x8 a0[NH], a1[NH];
#pragma unroll
            for (int hf=0; hf<NH; ++hf) {
                if (is_leaf) {
                    a0[hf] = *(const s16x8*)&h_lds[hf*16+lrow][kc*32+quad*8];   // el
                    a1[hf] = *(const s16x8*)&x_lds[hf*16+lrow][kc*32+quad*8];   // er
                } else {
                    int gn = nb + hf*16+lrow; if (gn>=n) gn=n-1;
                    a0[hf] = *(const s16x8*)(shadow + ((size_t)coff + (size_t)gn*8)*256 + kc*32+quad*8); // el
                    a1[hf] = *(const s16x8*)&h_lds[hf*16+lrow][kc*32+quad*8];   // er
                }
            }
            s16x8 b0 = *(const s16x8*)(we + (size_t)ce*512 + kc*32 + quad*8);
            s16x8 b1 = *(const s16x8*)(we + (size_t)ce*512 + 256 + kc*32 + quad*8);
#pragma unroll
            for (int hf=0; hf<NH; ++hf) {
                acc2[u2][hf] = MFMA(a0[hf], b0, acc2[u2][hf]);
                acc2[u2][hf] = MFMA(a1[hf], b1, acc2[u2][hf]);
            }
        }
    }
    __syncthreads();
    // scatter enc (bf16) into x_lds; root also writes fp32 dout
#pragma unroll
    for (int u2=0; u2<4; ++u2) {
        int ce = wv*64 + u2*16 + lrow;
#pragma unroll
        for (int hf=0; hf<NH; ++hf) {
#pragma unroll
            for (int r=0; r<4; ++r) {
                float v = tanh_(acc2[u2][hf][r]);
                int node = hf*16+quad*4+r;
                x_lds[node][ce] = (u16)f2bf(v);
                if (is_root && node==0) dout[ce] = v;
            }
        }
    }
    __syncthreads();
    // coalesced copyout x_lds -> shadow[off..]
    {
        int row = tid>>2;
        if (row < NH*16) {
            int gn = nb+row; if (gn>=n) gn=n-1;
            u16* d = shadow + (size_t)(off+gn)*256 + (tid&3)*64;
            const u16* s = &x_lds[row][(tid&3)*64];
#pragma unroll
            for (int q=0;q<8;++q) ((uint4*)d)[q] = ((const uint4*)s)[q];
        }
    }
}

extern "C" void kernel_launch(void* const* d_in, const int* in_sizes, int n_in,
                              void* d_out, int out_size, void* d_ws, size_t ws_size,
                              hipStream_t stream) {
    (void)in_sizes; (void)n_in; (void)out_size; (void)ws_size;
    const float* node_init = (const float*)d_in[0];
    const float* Wih_l = (const float*)d_in[1];
    const float* Whh_l = (const float*)d_in[2];
    const float* bih_l = (const float*)d_in[3];
    const float* bhh_l = (const float*)d_in[4];
    const float* Wih_r = (const float*)d_in[5];
    const float* Whh_r = (const float*)d_in[6];
    const float* bih_r = (const float*)d_in[7];
    const float* bhh_r = (const float*)d_in[8];
    const float* Wenc  = (const float*)d_in[9];
    const float* benc  = (const float*)d_in[10];

    u16* shadow = (u16*)d_ws;                      // 299593*256 bf16 = 153.4 MB
    u16* wil = shadow + (size_t)299593*256;
    u16* whl = wil + 262144;
    u16* wir = whl + 262144;
    u16* whr = wir + 262144;
    u16* we  = whr + 262144;                       // 131072
    float* bl = (float*)(we + 131072);
    float* br = bl + 1024;
    float* be = br + 1024;

    conv_nodes<<<dim3(8192), dim3(256), 0, stream>>>(node_init, shadow, 9586976L);
    prep_weights<<<dim3(1537), dim3(256), 0, stream>>>(
        Wih_l, Whh_l, bih_l, bhh_l, Wih_r, Whh_r, bih_r, bhh_r, Wenc, benc,
        wil, whl, wir, whr, we, bl, br, be);

    static const int OFF[8] = {0, 1, 9, 73, 585, 4681, 37449, 299593};
    static const int SZ[7]  = {1, 8, 64, 512, 4096, 32768, 262144};

    for (int d = 6; d >= 0; --d) {
        const int n = SZ[d];
        const int T = (d == 6) ? 1 : 5;
        const int leaf = (d == 6) ? 1 : 0;
        const int root = (d == 0) ? 1 : 0;
        const int coff = (d < 6) ? OFF[d+1] : 0;
        if (d >= 5) {
            level_kernel<4><<<dim3((n+63)/64), dim3(256), 0, stream>>>(
                shadow, wil, whl, wir, whr, we, bl, br, be,
                (float*)d_out, OFF[d], coff, n, T, leaf, root);
        } else {
            level_kernel<1><<<dim3((n+15)/16), dim3(256), 0, stream>>>(
                shadow, wil, whl, wir, whr, we, bl, br, be,
                (float*)d_out, OFF[d], coff, n, T, leaf, root);
        }
    }
}

// Round 4
// 8573.485 us; speedup vs baseline: 1.2057x; 1.2057x over previous
//
#include <hip/hip_runtime.h>
#include <cstdint>
#include <cstddef>

typedef unsigned int u32;
typedef unsigned short u16;
typedef __attribute__((ext_vector_type(8))) short s16x8;
typedef __attribute__((ext_vector_type(4))) float f32x4;

#define MFMA(a,b,c) __builtin_amdgcn_mfma_f32_16x16x32_bf16((a),(b),(c),0,0,0)

__device__ __forceinline__ u32 f2bf(float f){ union{float f;u32 u;}v; v.f=f; return (v.u + 0x7FFFu + ((v.u>>16)&1u))>>16; }
__device__ __forceinline__ float bflo(u32 p){ union{u32 u;float f;}v; v.u=p<<16; return v.f; }
__device__ __forceinline__ float bfhi(u32 p){ union{u32 u;float f;}v; v.u=p&0xFFFF0000u; return v.f; }
__device__ __forceinline__ float sigm(float x){ return __builtin_amdgcn_rcpf(1.0f + __builtin_amdgcn_exp2f(-1.4426950408889634f*x)); }
__device__ __forceinline__ float tanh_(float x){ return 1.0f - 2.0f*__builtin_amdgcn_rcpf(1.0f + __builtin_amdgcn_exp2f(2.8853900817779268f*x)); }

// node_init (fp32) -> shadow (bf16) for non-leaf own rows [0, 37449). total8 = elems/8.
__global__ void conv_nodes(const float* __restrict__ src, u16* __restrict__ dst, long total8) {
    long i = (long)blockIdx.x*256 + threadIdx.x;
    if (i < total8) {
        const float* s = src + i*8;
        float4 f0 = *(const float4*)s;
        float4 f1 = *(const float4*)(s+4);
        uint4 pk;
        pk.x = f2bf(f0.x) | (f2bf(f0.y)<<16);
        pk.y = f2bf(f0.z) | (f2bf(f0.w)<<16);
        pk.z = f2bf(f1.x) | (f2bf(f1.y)<<16);
        pk.w = f2bf(f1.z) | (f2bf(f1.w)<<16);
        *(uint4*)(dst + i*8) = pk;
    }
}

// Gate-interleaved row permutation: permuted row p -> source row
// p = wv*256 + gate*64 + u*16 + lrow  <->  source row = gate*256 + (wv*64 + u*16 + lrow)
__device__ __forceinline__ int srcrow(int p){ return ((p>>6)&3)*256 + ((p>>8)<<6) + (p&63); }

__global__ void prep_weights(const float* Wih_l, const float* Whh_l, const float* bih_l, const float* bhh_l,
                             const float* Wih_r, const float* Whh_r, const float* bih_r, const float* bhh_r,
                             const float* Wenc, const float* benc,
                             u16* wil, u16* whl, u16* wir, u16* whr, u16* we,
                             float* bl, float* br, float* be) {
    const int b = blockIdx.x, t = threadIdx.x;
    if (b < 1024) {
        int s = srcrow(b)*256 + t;
        int d = b*256 + t;
        wil[d]=(u16)f2bf(Wih_l[s]); whl[d]=(u16)f2bf(Whh_l[s]);
        wir[d]=(u16)f2bf(Wih_r[s]); whr[d]=(u16)f2bf(Whh_r[s]);
    } else if (b < 1536) {
        int e = (b-1024)*256 + t;
        we[e] = (u16)f2bf(Wenc[e]);
    } else {
        for (int j=0;j<4;++j){ int p=j*256+t; int s=srcrow(p); bl[p]=bih_l[s]+bhh_l[s]; br[p]=bih_r[s]+bhh_r[s]; }
        be[t] = benc[t];
    }
}

// One tree level. WG = NH*16 nodes, 256 threads (4 waves). Wave wv computes all 4
// gates for features [wv*64, wv*64+64) via gate-interleaved weights; cell update in
// registers (c packed bf16x2); h deferred-scattered to LDS.
template<int NH>
__launch_bounds__(256, 1)   // cap 512: must not spill; actual alloc ~200-230 -> 2 WGs/CU
__global__ void level_kernel(const float* __restrict__ node_init, u16* __restrict__ shadow,
    const u16* __restrict__ wil, const u16* __restrict__ whl,
    const u16* __restrict__ wir, const u16* __restrict__ whr,
    const u16* __restrict__ we, const float* __restrict__ bl,
    const float* __restrict__ br, const float* __restrict__ be,
    float* __restrict__ dout,
    int off, int coff, int n, int T, int is_leaf, int is_root)
{
    __shared__ u16 x_lds[NH*16][264];
    __shared__ u16 h_lds[NH*16][264];

    const int tid = threadIdx.x;
    const int wv = tid>>6, lane = tid&63, lrow = lane&15, quad = lane>>4;
    const int nb = blockIdx.x * (NH*16);

    u32 c_pack[4*NH*2];   // bf16x2 c-state
    u32 h_pack[4*NH*2];   // bf16x2 pending h

    for (int side=0; side<2; ++side) {
        const u16* Wih = side? wir : wil;
        const u16* Whh = side? whr : whl;
        const float* bias = side? br : bl;
        for (int t=0; t<T; ++t) {
            // ---- stage phase: flush prev h_pack -> h_lds; stage x tile ----
            const bool wr_h = (t>0) || (side==1 && is_leaf);
            if (wr_h) {
#pragma unroll
                for (int u=0; u<4; ++u)
#pragma unroll
                for (int hf=0; hf<NH; ++hf)
#pragma unroll
                for (int rp=0; rp<2; ++rp) {
                    u32 p = h_pack[(u*NH+hf)*2+rp];
                    int node = hf*16 + quad*4 + rp*2;
                    int col = wv*64 + u*16 + lrow;
                    h_lds[node][col]   = (u16)p;
                    h_lds[node+1][col] = (u16)(p>>16);
                }
            }
            if (!(is_leaf && side==1)) {   // leaf side1 reuses own already in x_lds
                int row = tid>>2;
                if (row < NH*16) {
                    int gn = nb + row; if (gn>=n) gn = n-1;
                    if (is_leaf) {
                        const float* s = node_init + (size_t)(off+gn)*256 + (tid&3)*64;
                        u16* d = &x_lds[row][(tid&3)*64];
#pragma unroll
                        for (int q=0;q<8;++q) {
                            float4 f0 = ((const float4*)s)[q*2];
                            float4 f1 = ((const float4*)s)[q*2+1];
                            uint4 pk;
                            pk.x = f2bf(f0.x)|(f2bf(f0.y)<<16);
                            pk.y = f2bf(f0.z)|(f2bf(f0.w)<<16);
                            pk.z = f2bf(f1.x)|(f2bf(f1.y)<<16);
                            pk.w = f2bf(f1.z)|(f2bf(f1.w)<<16);
                            ((uint4*)d)[q] = pk;
                        }
                    } else {
                        const bool own = (side==0 ? (t==T-1) : (t==0));
                        int cidx = (side==0)? (3-t) : (3+t);
                        size_t grow = own ? (size_t)(off+gn) : ((size_t)coff + (size_t)gn*8 + cidx);
                        const u16* s = shadow + grow*256 + (tid&3)*64;
                        u16* d = &x_lds[row][(tid&3)*64];
#pragma unroll
                        for (int q=0;q<8;++q) ((uint4*)d)[q] = ((const uint4*)s)[q];
                    }
                }
            }
            __syncthreads();

            // ---- GEMM (x@Wih^T [+ h@Whh^T]) + in-register cell update ----
            const bool el_glob = (!is_leaf) && side==0 && t==T-1;
#pragma unroll
            for (int u=0; u<4; ++u) {
                f32x4 acc[4][NH];
#pragma unroll
                for (int g=0; g<4; ++g) {
                    float bv = bias[wv*256 + g*64 + u*16 + lrow];
#pragma unroll
                    for (int hf=0; hf<NH; ++hf) acc[g][hf] = (f32x4){bv,bv,bv,bv};
                }
#pragma unroll
                for (int kc=0; kc<8; ++kc) {
                    s16x8 a[NH];
#pragma unroll
                    for (int hf=0; hf<NH; ++hf)
                        a[hf] = *(const s16x8*)&x_lds[hf*16+lrow][kc*32 + quad*8];
#pragma unroll
                    for (int g=0; g<4; ++g) {
                        s16x8 bw = *(const s16x8*)(Wih + (size_t)(wv*256+g*64+u*16+lrow)*256 + kc*32 + quad*8);
#pragma unroll
                        for (int hf=0; hf<NH; ++hf) acc[g][hf] = MFMA(a[hf], bw, acc[g][hf]);
                    }
                }
                if (t>0) {
#pragma unroll
                    for (int kc=0; kc<8; ++kc) {
                        s16x8 a[NH];
#pragma unroll
                        for (int hf=0; hf<NH; ++hf)
                            a[hf] = *(const s16x8*)&h_lds[hf*16+lrow][kc*32 + quad*8];
#pragma unroll
                        for (int g=0; g<4; ++g) {
                            s16x8 bw = *(const s16x8*)(Whh + (size_t)(wv*256+g*64+u*16+lrow)*256 + kc*32 + quad*8);
#pragma unroll
                            for (int hf=0; hf<NH; ++hf) acc[g][hf] = MFMA(a[hf], bw, acc[g][hf]);
                        }
                    }
                }
#pragma unroll
                for (int hf=0; hf<NH; ++hf) {
#pragma unroll
                    for (int rp=0; rp<2; ++rp) {
                        int r0 = rp*2, r1 = rp*2+1;
                        float iv0 = sigm(acc[0][hf][r0]), iv1 = sigm(acc[0][hf][r1]);
                        float fv0 = sigm(acc[1][hf][r0]), fv1 = sigm(acc[1][hf][r1]);
                        float gv0 = tanh_(acc[2][hf][r0]), gv1 = tanh_(acc[2][hf][r1]);
                        float ov0 = sigm(acc[3][hf][r0]), ov1 = sigm(acc[3][hf][r1]);
                        int pi = (u*NH+hf)*2 + rp;
                        float c0 = iv0*gv0, c1 = iv1*gv1;
                        if (t>0) { u32 cp = c_pack[pi]; c0 += fv0*bflo(cp); c1 += fv1*bfhi(cp); }
                        c_pack[pi] = f2bf(c0) | (f2bf(c1)<<16);
                        float h0 = ov0*tanh_(c0), h1 = ov1*tanh_(c1);
                        u32 hb = f2bf(h0) | (f2bf(h1)<<16);
                        if (el_glob) {
                            int node = hf*16+quad*4+r0;
                            int gn0 = nb+node;   if (gn0>=n) gn0=n-1;
                            int gn1 = nb+node+1; if (gn1>=n) gn1=n-1;
                            int col = wv*64+u*16+lrow;
                            shadow[((size_t)coff + (size_t)gn0*8)*256 + col] = (u16)hb;
                            shadow[((size_t)coff + (size_t)gn1*8)*256 + col] = (u16)(hb>>16);
                        } else {
                            h_pack[pi] = hb;
                        }
                    }
                }
            }
            __syncthreads();
        } // t
    } // side

    // ---- encoder: scatter er (h_pack) -> (leaf? x_lds : h_lds) ----
#pragma unroll
    for (int u=0; u<4; ++u)
#pragma unroll
    for (int hf=0; hf<NH; ++hf)
#pragma unroll
    for (int rp=0; rp<2; ++rp) {
        u32 p = h_pack[(u*NH+hf)*2+rp];
        int node = hf*16 + quad*4 + rp*2;
        int col = wv*64 + u*16 + lrow;
        u16* d0 = is_leaf ? &x_lds[node][col] : &h_lds[node][col];
        d0[0]   = (u16)p;
        d0[264] = (u16)(p>>16);
    }
    __syncthreads();

    f32x4 acc2[4][NH];
#pragma unroll
    for (int u2=0; u2<4; ++u2) {
        int ce = wv*64 + u2*16 + lrow;
        float bv = be[ce];
#pragma unroll
        for (int hf=0; hf<NH; ++hf) acc2[u2][hf] = (f32x4){bv,bv,bv,bv};
#pragma unroll
        for (int kc=0; kc<8; ++kc) {
            s16x8 a0[NH], a1[NH];
#pragma unroll
            for (int hf=0; hf<NH; ++hf) {
                if (is_leaf) {
                    a0[hf] = *(const s16x8*)&h_lds[hf*16+lrow][kc*32+quad*8];   // el
                    a1[hf] = *(const s16x8*)&x_lds[hf*16+lrow][kc*32+quad*8];   // er
                } else {
                    int gn = nb + hf*16+lrow; if (gn>=n) gn=n-1;
                    a0[hf] = *(const s16x8*)(shadow + ((size_t)coff + (size_t)gn*8)*256 + kc*32+quad*8); // el
                    a1[hf] = *(const s16x8*)&h_lds[hf*16+lrow][kc*32+quad*8];   // er
                }
            }
            s16x8 b0 = *(const s16x8*)(we + (size_t)ce*512 + kc*32 + quad*8);
            s16x8 b1 = *(const s16x8*)(we + (size_t)ce*512 + 256 + kc*32 + quad*8);
#pragma unroll
            for (int hf=0; hf<NH; ++hf) {
                acc2[u2][hf] = MFMA(a0[hf], b0, acc2[u2][hf]);
                acc2[u2][hf] = MFMA(a1[hf], b1, acc2[u2][hf]);
            }
        }
    }
    __syncthreads();
    // scatter enc (bf16) into x_lds; root also writes fp32 dout
#pragma unroll
    for (int u2=0; u2<4; ++u2) {
        int ce = wv*64 + u2*16 + lrow;
#pragma unroll
        for (int hf=0; hf<NH; ++hf) {
#pragma unroll
            for (int r=0; r<4; ++r) {
                float v = tanh_(acc2[u2][hf][r]);
                int node = hf*16+quad*4+r;
                x_lds[node][ce] = (u16)f2bf(v);
                if (is_root && node==0) dout[ce] = v;
            }
        }
    }
    __syncthreads();
    // coalesced copyout x_lds -> shadow[off..]
    {
        int row = tid>>2;
        if (row < NH*16) {
            int gn = nb+row; if (gn>=n) gn=n-1;
            u16* d = shadow + (size_t)(off+gn)*256 + (tid&3)*64;
            const u16* s = &x_lds[row][(tid&3)*64];
#pragma unroll
            for (int q=0;q<8;++q) ((uint4*)d)[q] = ((const uint4*)s)[q];
        }
    }
}

extern "C" void kernel_launch(void* const* d_in, const int* in_sizes, int n_in,
                              void* d_out, int out_size, void* d_ws, size_t ws_size,
                              hipStream_t stream) {
    (void)in_sizes; (void)n_in; (void)out_size; (void)ws_size;
    const float* node_init = (const float*)d_in[0];
    const float* Wih_l = (const float*)d_in[1];
    const float* Whh_l = (const float*)d_in[2];
    const float* bih_l = (const float*)d_in[3];
    const float* bhh_l = (const float*)d_in[4];
    const float* Wih_r = (const float*)d_in[5];
    const float* Whh_r = (const float*)d_in[6];
    const float* bih_r = (const float*)d_in[7];
    const float* bhh_r = (const float*)d_in[8];
    const float* Wenc  = (const float*)d_in[9];
    const float* benc  = (const float*)d_in[10];

    u16* shadow = (u16*)d_ws;                      // 299593*256 bf16 = 153.4 MB
    u16* wil = shadow + (size_t)299593*256;
    u16* whl = wil + 262144;
    u16* wir = whl + 262144;
    u16* whr = wir + 262144;
    u16* we  = whr + 262144;                       // 131072
    float* bl = (float*)(we + 131072);
    float* br = bl + 1024;
    float* be = br + 1024;

    // convert only non-leaf own rows [0, 37449): 37449*256/8 = 1198368 chunks
    conv_nodes<<<dim3(4682), dim3(256), 0, stream>>>(node_init, shadow, 1198368L);
    prep_weights<<<dim3(1537), dim3(256), 0, stream>>>(
        Wih_l, Whh_l, bih_l, bhh_l, Wih_r, Whh_r, bih_r, bhh_r, Wenc, benc,
        wil, whl, wir, whr, we, bl, br, be);

    static const int OFF[8] = {0, 1, 9, 73, 585, 4681, 37449, 299593};
    static const int SZ[7]  = {1, 8, 64, 512, 4096, 32768, 262144};

    for (int d = 6; d >= 0; --d) {
        const int n = SZ[d];
        const int T = (d == 6) ? 1 : 5;
        const int leaf = (d == 6) ? 1 : 0;
        const int root = (d == 0) ? 1 : 0;
        const int coff = (d < 6) ? OFF[d+1] : 0;
        if (d >= 5) {
            level_kernel<4><<<dim3((n+63)/64), dim3(256), 0, stream>>>(
                node_init, shadow, wil, whl, wir, whr, we, bl, br, be,
                (float*)d_out, OFF[d], coff, n, T, leaf, root);
        } else {
            level_kernel<1><<<dim3((n+15)/16), dim3(256), 0, stream>>>(
                node_init, shadow, wil, whl, wir, whr, we, bl, br, be,
                (float*)d_out, OFF[d], coff, n, T, leaf, root);
        }
    }
}

// Round 5
// 4159.690 us; speedup vs baseline: 2.4850x; 2.0611x over previous
//
#include <hip/hip_runtime.h>
#include <cstdint>
#include <cstddef>

typedef unsigned int u32;
typedef unsigned short u16;
typedef __attribute__((ext_vector_type(8))) short s16x8;
typedef __attribute__((ext_vector_type(4))) float f32x4;

#define MFMA(a,b,c) __builtin_amdgcn_mfma_f32_16x16x32_bf16((a),(b),(c),0,0,0)

__device__ __forceinline__ u32 f2bf(float f){ union{float f;u32 u;}v; v.f=f; return (v.u + 0x7FFFu + ((v.u>>16)&1u))>>16; }
__device__ __forceinline__ float bflo(u32 p){ union{u32 u;float f;}v; v.u=p<<16; return v.f; }
__device__ __forceinline__ float bfhi(u32 p){ union{u32 u;float f;}v; v.u=p&0xFFFF0000u; return v.f; }
__device__ __forceinline__ float sigm(float x){ return __builtin_amdgcn_rcpf(1.0f + __builtin_amdgcn_exp2f(-1.4426950408889634f*x)); }
__device__ __forceinline__ float tanh_(float x){ return 1.0f - 2.0f*__builtin_amdgcn_rcpf(1.0f + __builtin_amdgcn_exp2f(2.8853900817779268f*x)); }

// node_init (fp32) -> shadow (bf16) for non-leaf own rows [0, 37449). total8 = elems/8.
__global__ void conv_nodes(const float* __restrict__ src, u16* __restrict__ dst, long total8) {
    long i = (long)blockIdx.x*256 + threadIdx.x;
    if (i < total8) {
        const float* s = src + i*8;
        float4 f0 = *(const float4*)s;
        float4 f1 = *(const float4*)(s+4);
        uint4 pk;
        pk.x = f2bf(f0.x) | (f2bf(f0.y)<<16);
        pk.y = f2bf(f0.z) | (f2bf(f0.w)<<16);
        pk.z = f2bf(f1.x) | (f2bf(f1.y)<<16);
        pk.w = f2bf(f1.z) | (f2bf(f1.w)<<16);
        *(uint4*)(dst + i*8) = pk;
    }
}

// Gate-interleaved row permutation: permuted row p -> source row
// p = wv*256 + gate*64 + u*16 + lrow  <->  source row = gate*256 + (wv*64 + u*16 + lrow)
__device__ __forceinline__ int srcrow(int p){ return ((p>>6)&3)*256 + ((p>>8)<<6) + (p&63); }

__global__ void prep_weights(const float* Wih_l, const float* Whh_l, const float* bih_l, const float* bhh_l,
                             const float* Wih_r, const float* Whh_r, const float* bih_r, const float* bhh_r,
                             const float* Wenc, const float* benc,
                             u16* wil, u16* whl, u16* wir, u16* whr, u16* we,
                             float* bl, float* br, float* be) {
    const int b = blockIdx.x, t = threadIdx.x;
    if (b < 1024) {
        int s = srcrow(b)*256 + t;
        int d = b*256 + t;
        wil[d]=(u16)f2bf(Wih_l[s]); whl[d]=(u16)f2bf(Whh_l[s]);
        wir[d]=(u16)f2bf(Wih_r[s]); whr[d]=(u16)f2bf(Whh_r[s]);
    } else if (b < 1536) {
        int e = (b-1024)*256 + t;
        we[e] = (u16)f2bf(Wenc[e]);
    } else {
        for (int j=0;j<4;++j){ int p=j*256+t; int s=srcrow(p); bl[p]=bih_l[s]+bhh_l[s]; br[p]=bih_r[s]+bhh_r[s]; }
        be[t] = benc[t];
    }
}

// One tree level. WG = NH*16 nodes, 256 threads (4 waves). Wave wv computes all 4
// gates for features [wv*64, wv*64+64) via gate-interleaved weights; cell update in
// registers (c packed bf16x2); h deferred-scattered to LDS.
// sched_barrier(0) after each u-subtile serializes the 4 subtiles so only one
// acc[4][NH] block (64 VGPRs) is live at a time -> no spill.
template<int NH>
__launch_bounds__(256, 1)
__global__ void level_kernel(const float* __restrict__ node_init, u16* __restrict__ shadow,
    const u16* __restrict__ wil, const u16* __restrict__ whl,
    const u16* __restrict__ wir, const u16* __restrict__ whr,
    const u16* __restrict__ we, const float* __restrict__ bl,
    const float* __restrict__ br, const float* __restrict__ be,
    float* __restrict__ dout,
    int off, int coff, int n, int T, int is_leaf, int is_root)
{
    __shared__ u16 x_lds[NH*16][264];
    __shared__ u16 h_lds[NH*16][264];

    const int tid = threadIdx.x;
    const int wv = tid>>6, lane = tid&63, lrow = lane&15, quad = lane>>4;
    const int nb = blockIdx.x * (NH*16);

    u32 c_pack[4*NH*2];   // bf16x2 c-state
    u32 h_pack[4*NH*2];   // bf16x2 pending h

    for (int side=0; side<2; ++side) {
        const u16* Wih = side? wir : wil;
        const u16* Whh = side? whr : whl;
        const float* bias = side? br : bl;
        for (int t=0; t<T; ++t) {
            // ---- stage phase: flush prev h_pack -> h_lds; stage x tile ----
            const bool wr_h = (t>0) || (side==1 && is_leaf);
            if (wr_h) {
#pragma unroll
                for (int u=0; u<4; ++u)
#pragma unroll
                for (int hf=0; hf<NH; ++hf)
#pragma unroll
                for (int rp=0; rp<2; ++rp) {
                    u32 p = h_pack[(u*NH+hf)*2+rp];
                    int node = hf*16 + quad*4 + rp*2;
                    int col = wv*64 + u*16 + lrow;
                    h_lds[node][col]   = (u16)p;
                    h_lds[node+1][col] = (u16)(p>>16);
                }
            }
            if (!(is_leaf && side==1)) {   // leaf side1 reuses own already in x_lds
                int row = tid>>2;
                if (row < NH*16) {
                    int gn = nb + row; if (gn>=n) gn = n-1;
                    if (is_leaf) {
                        const float* s = node_init + (size_t)(off+gn)*256 + (tid&3)*64;
                        u16* d = &x_lds[row][(tid&3)*64];
#pragma unroll
                        for (int q=0;q<8;++q) {
                            float4 f0 = ((const float4*)s)[q*2];
                            float4 f1 = ((const float4*)s)[q*2+1];
                            uint4 pk;
                            pk.x = f2bf(f0.x)|(f2bf(f0.y)<<16);
                            pk.y = f2bf(f0.z)|(f2bf(f0.w)<<16);
                            pk.z = f2bf(f1.x)|(f2bf(f1.y)<<16);
                            pk.w = f2bf(f1.z)|(f2bf(f1.w)<<16);
                            ((uint4*)d)[q] = pk;
                        }
                    } else {
                        const bool own = (side==0 ? (t==T-1) : (t==0));
                        int cidx = (side==0)? (3-t) : (3+t);
                        size_t grow = own ? (size_t)(off+gn) : ((size_t)coff + (size_t)gn*8 + cidx);
                        const u16* s = shadow + grow*256 + (tid&3)*64;
                        u16* d = &x_lds[row][(tid&3)*64];
#pragma unroll
                        for (int q=0;q<8;++q) ((uint4*)d)[q] = ((const uint4*)s)[q];
                    }
                }
            }
            __syncthreads();

            // ---- GEMM (x@Wih^T [+ h@Whh^T]) + in-register cell update ----
            const bool el_glob = (!is_leaf) && side==0 && t==T-1;
#pragma unroll
            for (int u=0; u<4; ++u) {
                f32x4 acc[4][NH];
#pragma unroll
                for (int g=0; g<4; ++g) {
                    float bv = bias[wv*256 + g*64 + u*16 + lrow];
#pragma unroll
                    for (int hf=0; hf<NH; ++hf) acc[g][hf] = (f32x4){bv,bv,bv,bv};
                }
#pragma unroll 2
                for (int kc=0; kc<8; ++kc) {
                    s16x8 a[NH];
#pragma unroll
                    for (int hf=0; hf<NH; ++hf)
                        a[hf] = *(const s16x8*)&x_lds[hf*16+lrow][kc*32 + quad*8];
#pragma unroll
                    for (int g=0; g<4; ++g) {
                        s16x8 bw = *(const s16x8*)(Wih + (size_t)(wv*256+g*64+u*16+lrow)*256 + kc*32 + quad*8);
#pragma unroll
                        for (int hf=0; hf<NH; ++hf) acc[g][hf] = MFMA(a[hf], bw, acc[g][hf]);
                    }
                }
                if (t>0) {
#pragma unroll 2
                    for (int kc=0; kc<8; ++kc) {
                        s16x8 a[NH];
#pragma unroll
                        for (int hf=0; hf<NH; ++hf)
                            a[hf] = *(const s16x8*)&h_lds[hf*16+lrow][kc*32 + quad*8];
#pragma unroll
                        for (int g=0; g<4; ++g) {
                            s16x8 bw = *(const s16x8*)(Whh + (size_t)(wv*256+g*64+u*16+lrow)*256 + kc*32 + quad*8);
#pragma unroll
                            for (int hf=0; hf<NH; ++hf) acc[g][hf] = MFMA(a[hf], bw, acc[g][hf]);
                        }
                    }
                }
#pragma unroll
                for (int hf=0; hf<NH; ++hf) {
#pragma unroll
                    for (int rp=0; rp<2; ++rp) {
                        int r0 = rp*2, r1 = rp*2+1;
                        float iv0 = sigm(acc[0][hf][r0]), iv1 = sigm(acc[0][hf][r1]);
                        float fv0 = sigm(acc[1][hf][r0]), fv1 = sigm(acc[1][hf][r1]);
                        float gv0 = tanh_(acc[2][hf][r0]), gv1 = tanh_(acc[2][hf][r1]);
                        float ov0 = sigm(acc[3][hf][r0]), ov1 = sigm(acc[3][hf][r1]);
                        int pi = (u*NH+hf)*2 + rp;
                        float c0 = iv0*gv0, c1 = iv1*gv1;
                        if (t>0) { u32 cp = c_pack[pi]; c0 += fv0*bflo(cp); c1 += fv1*bfhi(cp); }
                        c_pack[pi] = f2bf(c0) | (f2bf(c1)<<16);
                        float h0 = ov0*tanh_(c0), h1 = ov1*tanh_(c1);
                        u32 hb = f2bf(h0) | (f2bf(h1)<<16);
                        if (el_glob) {
                            int node = hf*16+quad*4+r0;
                            int gn0 = nb+node;   if (gn0>=n) gn0=n-1;
                            int gn1 = nb+node+1; if (gn1>=n) gn1=n-1;
                            int col = wv*64+u*16+lrow;
                            shadow[((size_t)coff + (size_t)gn0*8)*256 + col] = (u16)hb;
                            shadow[((size_t)coff + (size_t)gn1*8)*256 + col] = (u16)(hb>>16);
                        } else {
                            h_pack[pi] = hb;
                        }
                    }
                }
                __builtin_amdgcn_sched_barrier(0);   // serialize u-subtiles: cap live regs
            }
            __syncthreads();
        } // t
    } // side

    // ---- encoder: scatter er (h_pack) -> (leaf? x_lds : h_lds) ----
#pragma unroll
    for (int u=0; u<4; ++u)
#pragma unroll
    for (int hf=0; hf<NH; ++hf)
#pragma unroll
    for (int rp=0; rp<2; ++rp) {
        u32 p = h_pack[(u*NH+hf)*2+rp];
        int node = hf*16 + quad*4 + rp*2;
        int col = wv*64 + u*16 + lrow;
        u16* d0 = is_leaf ? &x_lds[node][col] : &h_lds[node][col];
        d0[0]   = (u16)p;
        d0[264] = (u16)(p>>16);
    }
    __syncthreads();

    f32x4 acc2[4][NH];
#pragma unroll
    for (int u2=0; u2<4; ++u2) {
        int ce = wv*64 + u2*16 + lrow;
        float bv = be[ce];
#pragma unroll
        for (int hf=0; hf<NH; ++hf) acc2[u2][hf] = (f32x4){bv,bv,bv,bv};
#pragma unroll 2
        for (int kc=0; kc<8; ++kc) {
            s16x8 a0[NH], a1[NH];
#pragma unroll
            for (int hf=0; hf<NH; ++hf) {
                if (is_leaf) {
                    a0[hf] = *(const s16x8*)&h_lds[hf*16+lrow][kc*32+quad*8];   // el
                    a1[hf] = *(const s16x8*)&x_lds[hf*16+lrow][kc*32+quad*8];   // er
                } else {
                    int gn = nb + hf*16+lrow; if (gn>=n) gn=n-1;
                    a0[hf] = *(const s16x8*)(shadow + ((size_t)coff + (size_t)gn*8)*256 + kc*32+quad*8); // el
                    a1[hf] = *(const s16x8*)&h_lds[hf*16+lrow][kc*32+quad*8];   // er
                }
            }
            s16x8 b0 = *(const s16x8*)(we + (size_t)ce*512 + kc*32 + quad*8);
            s16x8 b1 = *(const s16x8*)(we + (size_t)ce*512 + 256 + kc*32 + quad*8);
#pragma unroll
            for (int hf=0; hf<NH; ++hf) {
                acc2[u2][hf] = MFMA(a0[hf], b0, acc2[u2][hf]);
                acc2[u2][hf] = MFMA(a1[hf], b1, acc2[u2][hf]);
            }
        }
        __builtin_amdgcn_sched_barrier(0);
    }
    __syncthreads();
    // scatter enc (bf16) into x_lds; root also writes fp32 dout
#pragma unroll
    for (int u2=0; u2<4; ++u2) {
        int ce = wv*64 + u2*16 + lrow;
#pragma unroll
        for (int hf=0; hf<NH; ++hf) {
#pragma unroll
            for (int r=0; r<4; ++r) {
                float v = tanh_(acc2[u2][hf][r]);
                int node = hf*16+quad*4+r;
                x_lds[node][ce] = (u16)f2bf(v);
                if (is_root && node==0) dout[ce] = v;
            }
        }
    }
    __syncthreads();
    // coalesced copyout x_lds -> shadow[off..]
    {
        int row = tid>>2;
        if (row < NH*16) {
            int gn = nb+row; if (gn>=n) gn=n-1;
            u16* d = shadow + (size_t)(off+gn)*256 + (tid&3)*64;
            const u16* s = &x_lds[row][(tid&3)*64];
#pragma unroll
            for (int q=0;q<8;++q) ((uint4*)d)[q] = ((const uint4*)s)[q];
        }
    }
}

extern "C" void kernel_launch(void* const* d_in, const int* in_sizes, int n_in,
                              void* d_out, int out_size, void* d_ws, size_t ws_size,
                              hipStream_t stream) {
    (void)in_sizes; (void)n_in; (void)out_size; (void)ws_size;
    const float* node_init = (const float*)d_in[0];
    const float* Wih_l = (const float*)d_in[1];
    const float* Whh_l = (const float*)d_in[2];
    const float* bih_l = (const float*)d_in[3];
    const float* bhh_l = (const float*)d_in[4];
    const float* Wih_r = (const float*)d_in[5];
    const float* Whh_r = (const float*)d_in[6];
    const float* bih_r = (const float*)d_in[7];
    const float* bhh_r = (const float*)d_in[8];
    const float* Wenc  = (const float*)d_in[9];
    const float* benc  = (const float*)d_in[10];

    u16* shadow = (u16*)d_ws;                      // 299593*256 bf16 = 153.4 MB
    u16* wil = shadow + (size_t)299593*256;
    u16* whl = wil + 262144;
    u16* wir = whl + 262144;
    u16* whr = wir + 262144;
    u16* we  = whr + 262144;                       // 131072
    float* bl = (float*)(we + 131072);
    float* br = bl + 1024;
    float* be = br + 1024;

    // convert only non-leaf own rows [0, 37449): 37449*256/8 = 1198368 chunks
    conv_nodes<<<dim3(4682), dim3(256), 0, stream>>>(node_init, shadow, 1198368L);
    prep_weights<<<dim3(1537), dim3(256), 0, stream>>>(
        Wih_l, Whh_l, bih_l, bhh_l, Wih_r, Whh_r, bih_r, bhh_r, Wenc, benc,
        wil, whl, wir, whr, we, bl, br, be);

    static const int OFF[8] = {0, 1, 9, 73, 585, 4681, 37449, 299593};
    static const int SZ[7]  = {1, 8, 64, 512, 4096, 32768, 262144};

    for (int d = 6; d >= 0; --d) {
        const int n = SZ[d];
        const int T = (d == 6) ? 1 : 5;
        const int leaf = (d == 6) ? 1 : 0;
        const int root = (d == 0) ? 1 : 0;
        const int coff = (d < 6) ? OFF[d+1] : 0;
        if (d >= 5) {
            level_kernel<4><<<dim3((n+63)/64), dim3(256), 0, stream>>>(
                node_init, shadow, wil, whl, wir, whr, we, bl, br, be,
                (float*)d_out, OFF[d], coff, n, T, leaf, root);
        } else {
            level_kernel<1><<<dim3((n+15)/16), dim3(256), 0, stream>>>(
                node_init, shadow, wil, whl, wir, whr, we, bl, br, be,
                (float*)d_out, OFF[d], coff, n, T, leaf, root);
        }
    }
}

// Round 6
// 2818.853 us; speedup vs baseline: 3.6671x; 1.4757x over previous
//
#include <hip/hip_runtime.h>
#include <cstdint>
#include <cstddef>

typedef unsigned int u32;
typedef unsigned short u16;
typedef __attribute__((ext_vector_type(8))) short s16x8;
typedef __attribute__((ext_vector_type(4))) float f32x4;

#define MFMA(a,b,c) __builtin_amdgcn_mfma_f32_16x16x32_bf16((a),(b),(c),0,0,0)

__device__ __forceinline__ u32 f2bf(float f){ union{float f;u32 u;}v; v.f=f; return (v.u + 0x7FFFu + ((v.u>>16)&1u))>>16; }
__device__ __forceinline__ float bflo(u32 p){ union{u32 u;float f;}v; v.u=p<<16; return v.f; }
__device__ __forceinline__ float bfhi(u32 p){ union{u32 u;float f;}v; v.u=p&0xFFFF0000u; return v.f; }
__device__ __forceinline__ float sigm(float x){ return __builtin_amdgcn_rcpf(1.0f + __builtin_amdgcn_exp2f(-1.4426950408889634f*x)); }
__device__ __forceinline__ float tanh_(float x){ return 1.0f - 2.0f*__builtin_amdgcn_rcpf(1.0f + __builtin_amdgcn_exp2f(2.8853900817779268f*x)); }

// node_init (fp32) -> shadow (bf16) for non-leaf own rows [0, 37449). total8 = elems/8.
__global__ void conv_nodes(const float* __restrict__ src, u16* __restrict__ dst, long total8) {
    long i = (long)blockIdx.x*256 + threadIdx.x;
    if (i < total8) {
        const float* s = src + i*8;
        float4 f0 = *(const float4*)s;
        float4 f1 = *(const float4*)(s+4);
        uint4 pk;
        pk.x = f2bf(f0.x) | (f2bf(f0.y)<<16);
        pk.y = f2bf(f0.z) | (f2bf(f0.w)<<16);
        pk.z = f2bf(f1.x) | (f2bf(f1.y)<<16);
        pk.w = f2bf(f1.z) | (f2bf(f1.w)<<16);
        *(uint4*)(dst + i*8) = pk;
    }
}

// Packed weight layout (gather-free B-fragments):
// LSTM mats: block b = ((wv*4+u)*4+g)*8+kc, flat = b*512 + lane*8 + j
//   source row (torch order) = g*256 + wv*64 + u*16 + lrow, col = kc*32 + quad*8 + j
// Wenc: block = ((wv*4+u2)*2+half)*8+kc, flat = blk*512 + lane*8 + j
//   source row ce = wv*64+u2*16+lrow, col = half*256 + kc*32 + quad*8 + j
__global__ void prep_weights(const float* Wih_l, const float* Whh_l, const float* bih_l, const float* bhh_l,
                             const float* Wih_r, const float* Whh_r, const float* bih_r, const float* bhh_r,
                             const float* Wenc, const float* benc,
                             u16* wil, u16* whl, u16* wir, u16* whr, u16* we,
                             float* bl, float* br, float* be) {
    const int b = blockIdx.x, t = threadIdx.x;
    if (b < 1024) {
        int o = b*256 + t;                       // [0, 262144)
        int j = o & 7, lane = (o>>3)&63, blk = o>>9;
        int kc = blk&7, g = (blk>>3)&3, u = (blk>>5)&3, wv = blk>>7;
        int lrow = lane&15, quad = lane>>4;
        int s = (g*256 + wv*64 + u*16 + lrow)*256 + kc*32 + quad*8 + j;
        wil[o]=(u16)f2bf(Wih_l[s]); whl[o]=(u16)f2bf(Whh_l[s]);
        wir[o]=(u16)f2bf(Wih_r[s]); whr[o]=(u16)f2bf(Whh_r[s]);
    } else if (b < 1536) {
        int o = (b-1024)*256 + t;                // [0, 131072)
        int j = o & 7, lane = (o>>3)&63, blk = o>>9;
        int kc = blk&7, half = (blk>>3)&1, u2 = (blk>>4)&3, wv = blk>>6;
        int lrow = lane&15, quad = lane>>4;
        int s = (wv*64 + u2*16 + lrow)*512 + half*256 + kc*32 + quad*8 + j;
        we[o] = (u16)f2bf(Wenc[s]);
    } else {
        for (int jj=0;jj<4;++jj){
            int p = jj*256 + t;                  // p = wv*256+g*64+u*16+lrow
            int s = ((p>>6)&3)*256 + ((p>>8)<<6) + (p&63);
            bl[p]=bih_l[s]+bhh_l[s]; br[p]=bih_r[s]+bhh_r[s];
        }
        be[t] = benc[t];
    }
}

// One tree level. WG = NH*16 nodes, 256 threads (4 waves). Wave wv computes all 4
// gates for features [wv*64, wv*64+64) via gate-interleaved packed weights; cell
// update in registers (c packed bf16x2); h deferred-scattered to LDS.
// sched_barrier(0) per u-subtile keeps one acc block live at a time.
template<int NH>
__launch_bounds__(256, 2)
__global__ void level_kernel(const float* __restrict__ node_init, u16* __restrict__ shadow,
    const u16* __restrict__ wil, const u16* __restrict__ whl,
    const u16* __restrict__ wir, const u16* __restrict__ whr,
    const u16* __restrict__ we, const float* __restrict__ bl,
    const float* __restrict__ br, const float* __restrict__ be,
    float* __restrict__ dout,
    int off, int coff, int n, int T, int is_leaf, int is_root)
{
    __shared__ u16 x_lds[NH*16][264];
    __shared__ u16 h_lds[NH*16][264];

    const int tid = threadIdx.x;
    const int wv = tid>>6, lane = tid&63, lrow = lane&15, quad = lane>>4;
    const int lane8 = lane*8;
    const int nb = blockIdx.x * (NH*16);

    u32 c_pack[4*NH*2];   // bf16x2 c-state
    u32 h_pack[4*NH*2];   // bf16x2 pending h

    for (int side=0; side<2; ++side) {
        const u16* Wih = side? wir : wil;
        const u16* Whh = side? whr : whl;
        const float* bias = side? br : bl;
        for (int t=0; t<T; ++t) {
            // ---- stage phase: flush prev h_pack -> h_lds; stage x tile ----
            const bool wr_h = (t>0) || (side==1 && is_leaf);
            if (wr_h) {
#pragma unroll
                for (int u=0; u<4; ++u)
#pragma unroll
                for (int hf=0; hf<NH; ++hf)
#pragma unroll
                for (int rp=0; rp<2; ++rp) {
                    u32 p = h_pack[(u*NH+hf)*2+rp];
                    int node = hf*16 + quad*4 + rp*2;
                    int col = wv*64 + u*16 + lrow;
                    h_lds[node][col]   = (u16)p;
                    h_lds[node+1][col] = (u16)(p>>16);
                }
            }
            if (!(is_leaf && side==1)) {   // leaf side1 reuses own already in x_lds
                int row = tid>>2;
                if (row < NH*16) {
                    int gn = nb + row; if (gn>=n) gn = n-1;
                    if (is_leaf) {
                        const float* s = node_init + (size_t)(off+gn)*256 + (tid&3)*64;
                        u16* d = &x_lds[row][(tid&3)*64];
#pragma unroll
                        for (int q=0;q<8;++q) {
                            float4 f0 = ((const float4*)s)[q*2];
                            float4 f1 = ((const float4*)s)[q*2+1];
                            uint4 pk;
                            pk.x = f2bf(f0.x)|(f2bf(f0.y)<<16);
                            pk.y = f2bf(f0.z)|(f2bf(f0.w)<<16);
                            pk.z = f2bf(f1.x)|(f2bf(f1.y)<<16);
                            pk.w = f2bf(f1.z)|(f2bf(f1.w)<<16);
                            ((uint4*)d)[q] = pk;
                        }
                    } else {
                        const bool own = (side==0 ? (t==T-1) : (t==0));
                        int cidx = (side==0)? (3-t) : (3+t);
                        size_t grow = own ? (size_t)(off+gn) : ((size_t)coff + (size_t)gn*8 + cidx);
                        const u16* s = shadow + grow*256 + (tid&3)*64;
                        u16* d = &x_lds[row][(tid&3)*64];
#pragma unroll
                        for (int q=0;q<8;++q) ((uint4*)d)[q] = ((const uint4*)s)[q];
                    }
                }
            }
            __syncthreads();

            // ---- GEMM (x@Wih^T [+ h@Whh^T]) + in-register cell update ----
            const bool el_glob = (!is_leaf) && side==0 && t==T-1;
#pragma unroll
            for (int u=0; u<4; ++u) {
                const u16* Wu = Wih + (size_t)(wv*4+u)*16384;
                const u16* Hu = Whh + (size_t)(wv*4+u)*16384;
                f32x4 acc[4][NH];
#pragma unroll
                for (int g=0; g<4; ++g) {
                    float bv = bias[wv*256 + g*64 + u*16 + lrow];
#pragma unroll
                    for (int hf=0; hf<NH; ++hf) acc[g][hf] = (f32x4){bv,bv,bv,bv};
                }
#pragma unroll 2
                for (int kc=0; kc<8; ++kc) {
                    s16x8 a[NH];
#pragma unroll
                    for (int hf=0; hf<NH; ++hf)
                        a[hf] = *(const s16x8*)&x_lds[hf*16+lrow][kc*32 + quad*8];
#pragma unroll
                    for (int g=0; g<4; ++g) {
                        s16x8 bw = *(const s16x8*)(Wu + ((g*8+kc)<<9) + lane8);
#pragma unroll
                        for (int hf=0; hf<NH; ++hf) acc[g][hf] = MFMA(a[hf], bw, acc[g][hf]);
                    }
                }
                if (t>0) {
#pragma unroll 2
                    for (int kc=0; kc<8; ++kc) {
                        s16x8 a[NH];
#pragma unroll
                        for (int hf=0; hf<NH; ++hf)
                            a[hf] = *(const s16x8*)&h_lds[hf*16+lrow][kc*32 + quad*8];
#pragma unroll
                        for (int g=0; g<4; ++g) {
                            s16x8 bw = *(const s16x8*)(Hu + ((g*8+kc)<<9) + lane8);
#pragma unroll
                            for (int hf=0; hf<NH; ++hf) acc[g][hf] = MFMA(a[hf], bw, acc[g][hf]);
                        }
                    }
                }
#pragma unroll
                for (int hf=0; hf<NH; ++hf) {
#pragma unroll
                    for (int rp=0; rp<2; ++rp) {
                        int r0 = rp*2, r1 = rp*2+1;
                        float iv0 = sigm(acc[0][hf][r0]), iv1 = sigm(acc[0][hf][r1]);
                        float fv0 = sigm(acc[1][hf][r0]), fv1 = sigm(acc[1][hf][r1]);
                        float gv0 = tanh_(acc[2][hf][r0]), gv1 = tanh_(acc[2][hf][r1]);
                        float ov0 = sigm(acc[3][hf][r0]), ov1 = sigm(acc[3][hf][r1]);
                        int pi = (u*NH+hf)*2 + rp;
                        float c0 = iv0*gv0, c1 = iv1*gv1;
                        if (t>0) { u32 cp = c_pack[pi]; c0 += fv0*bflo(cp); c1 += fv1*bfhi(cp); }
                        c_pack[pi] = f2bf(c0) | (f2bf(c1)<<16);
                        float h0 = ov0*tanh_(c0), h1 = ov1*tanh_(c1);
                        u32 hb = f2bf(h0) | (f2bf(h1)<<16);
                        if (el_glob) {
                            int node = hf*16+quad*4+r0;
                            int gn0 = nb+node;   if (gn0>=n) gn0=n-1;
                            int gn1 = nb+node+1; if (gn1>=n) gn1=n-1;
                            int col = wv*64+u*16+lrow;
                            shadow[((size_t)coff + (size_t)gn0*8)*256 + col] = (u16)hb;
                            shadow[((size_t)coff + (size_t)gn1*8)*256 + col] = (u16)(hb>>16);
                        } else {
                            h_pack[pi] = hb;
                        }
                    }
                }
                __builtin_amdgcn_sched_barrier(0);   // serialize u-subtiles: cap live regs
            }
            __syncthreads();
        } // t
    } // side

    // ---- encoder: scatter er (h_pack) -> (leaf? x_lds : h_lds) ----
#pragma unroll
    for (int u=0; u<4; ++u)
#pragma unroll
    for (int hf=0; hf<NH; ++hf)
#pragma unroll
    for (int rp=0; rp<2; ++rp) {
        u32 p = h_pack[(u*NH+hf)*2+rp];
        int node = hf*16 + quad*4 + rp*2;
        int col = wv*64 + u*16 + lrow;
        u16* d0 = is_leaf ? &x_lds[node][col] : &h_lds[node][col];
        d0[0]   = (u16)p;
        d0[264] = (u16)(p>>16);
    }
    __syncthreads();

    f32x4 acc2[4][NH];
#pragma unroll
    for (int u2=0; u2<4; ++u2) {
        const u16* Eu = we + (size_t)(wv*4+u2)*8192;
        int ce = wv*64 + u2*16 + lrow;
        float bv = be[ce];
#pragma unroll
        for (int hf=0; hf<NH; ++hf) acc2[u2][hf] = (f32x4){bv,bv,bv,bv};
#pragma unroll 2
        for (int kc=0; kc<8; ++kc) {
            s16x8 a0[NH], a1[NH];
#pragma unroll
            for (int hf=0; hf<NH; ++hf) {
                if (is_leaf) {
                    a0[hf] = *(const s16x8*)&h_lds[hf*16+lrow][kc*32+quad*8];   // el
                    a1[hf] = *(const s16x8*)&x_lds[hf*16+lrow][kc*32+quad*8];   // er
                } else {
                    int gn = nb + hf*16+lrow; if (gn>=n) gn=n-1;
                    a0[hf] = *(const s16x8*)(shadow + ((size_t)coff + (size_t)gn*8)*256 + kc*32+quad*8); // el
                    a1[hf] = *(const s16x8*)&h_lds[hf*16+lrow][kc*32+quad*8];   // er
                }
            }
            s16x8 b0 = *(const s16x8*)(Eu + (kc<<9) + lane8);
            s16x8 b1 = *(const s16x8*)(Eu + ((8+kc)<<9) + lane8);
#pragma unroll
            for (int hf=0; hf<NH; ++hf) {
                acc2[u2][hf] = MFMA(a0[hf], b0, acc2[u2][hf]);
                acc2[u2][hf] = MFMA(a1[hf], b1, acc2[u2][hf]);
            }
        }
        __builtin_amdgcn_sched_barrier(0);
    }
    __syncthreads();
    // scatter enc (bf16) into x_lds; root also writes fp32 dout
#pragma unroll
    for (int u2=0; u2<4; ++u2) {
        int ce = wv*64 + u2*16 + lrow;
#pragma unroll
        for (int hf=0; hf<NH; ++hf) {
#pragma unroll
            for (int r=0; r<4; ++r) {
                float v = tanh_(acc2[u2][hf][r]);
                int node = hf*16+quad*4+r;
                x_lds[node][ce] = (u16)f2bf(v);
                if (is_root && node==0) dout[ce] = v;
            }
        }
    }
    __syncthreads();
    // coalesced copyout x_lds -> shadow[off..]
    {
        int row = tid>>2;
        if (row < NH*16) {
            int gn = nb+row; if (gn>=n) gn=n-1;
            u16* d = shadow + (size_t)(off+gn)*256 + (tid&3)*64;
            const u16* s = &x_lds[row][(tid&3)*64];
#pragma unroll
            for (int q=0;q<8;++q) ((uint4*)d)[q] = ((const uint4*)s)[q];
        }
    }
}

extern "C" void kernel_launch(void* const* d_in, const int* in_sizes, int n_in,
                              void* d_out, int out_size, void* d_ws, size_t ws_size,
                              hipStream_t stream) {
    (void)in_sizes; (void)n_in; (void)out_size; (void)ws_size;
    const float* node_init = (const float*)d_in[0];
    const float* Wih_l = (const float*)d_in[1];
    const float* Whh_l = (const float*)d_in[2];
    const float* bih_l = (const float*)d_in[3];
    const float* bhh_l = (const float*)d_in[4];
    const float* Wih_r = (const float*)d_in[5];
    const float* Whh_r = (const float*)d_in[6];
    const float* bih_r = (const float*)d_in[7];
    const float* bhh_r = (const float*)d_in[8];
    const float* Wenc  = (const float*)d_in[9];
    const float* benc  = (const float*)d_in[10];

    u16* shadow = (u16*)d_ws;                      // 299593*256 bf16 = 153.4 MB
    u16* wil = shadow + (size_t)299593*256;
    u16* whl = wil + 262144;
    u16* wir = whl + 262144;
    u16* whr = wir + 262144;
    u16* we  = whr + 262144;                       // 131072
    float* bl = (float*)(we + 131072);
    float* br = bl + 1024;
    float* be = br + 1024;

    // convert only non-leaf own rows [0, 37449): 37449*256/8 = 1198368 chunks
    conv_nodes<<<dim3(4682), dim3(256), 0, stream>>>(node_init, shadow, 1198368L);
    prep_weights<<<dim3(1537), dim3(256), 0, stream>>>(
        Wih_l, Whh_l, bih_l, bhh_l, Wih_r, Whh_r, bih_r, bhh_r, Wenc, benc,
        wil, whl, wir, whr, we, bl, br, be);

    static const int OFF[8] = {0, 1, 9, 73, 585, 4681, 37449, 299593};
    static const int SZ[7]  = {1, 8, 64, 512, 4096, 32768, 262144};

    for (int d = 6; d >= 0; --d) {
        const int n = SZ[d];
        const int T = (d == 6) ? 1 : 5;
        const int leaf = (d == 6) ? 1 : 0;
        const int root = (d == 0) ? 1 : 0;
        const int coff = (d < 6) ? OFF[d+1] : 0;
        if (d >= 5) {
            level_kernel<2><<<dim3((n+31)/32), dim3(256), 0, stream>>>(
                node_init, shadow, wil, whl, wir, whr, we, bl, br, be,
                (float*)d_out, OFF[d], coff, n, T, leaf, root);
        } else {
            level_kernel<1><<<dim3((n+15)/16), dim3(256), 0, stream>>>(
                node_init, shadow, wil, whl, wir, whr, we, bl, br, be,
                (float*)d_out, OFF[d], coff, n, T, leaf, root);
        }
    }
}